// Round 1
// baseline (171.287 us; speedup 1.0000x reference)
//
#include <hip/hip_runtime.h>

// InvertAffine: per sample, full = [[I+M, t],[0,1]] (4x4). Its inverse is
// [[B, -B t],[0,1]] with B = (I+M)^{-1}. Output = (inv - I)[:3,:] flattened,
// i.e. rows i: [B_i0-d_i0, B_i1-d_i1, B_i2-d_i2, -(B t)_i].
// 3x3 inverse via cofactors (well-conditioned: M entries ~N(0,0.1)).
// Memory-bound: 2M * 96 B = 192 MB total traffic.

__global__ __launch_bounds__(256) void invert_affine_kernel(
    const float4* __restrict__ in, float4* __restrict__ out, int b) {
  int i = blockIdx.x * blockDim.x + threadIdx.x;
  if (i >= b) return;

  // sample i occupies 12 floats = 3 float4's, contiguous & 16B-aligned
  float4 r0 = in[3 * i + 0];
  float4 r1 = in[3 * i + 1];
  float4 r2 = in[3 * i + 2];

  float a00 = r0.x + 1.0f, a01 = r0.y,        a02 = r0.z,        t0 = r0.w;
  float a10 = r1.x,        a11 = r1.y + 1.0f, a12 = r1.z,        t1 = r1.w;
  float a20 = r2.x,        a21 = r2.y,        a22 = r2.z + 1.0f, t2 = r2.w;

  // inverse entries (adjugate transposed already folded in)
  float b00 = a11 * a22 - a12 * a21;
  float b01 = a02 * a21 - a01 * a22;
  float b02 = a01 * a12 - a02 * a11;
  float b10 = a12 * a20 - a10 * a22;
  float b11 = a00 * a22 - a02 * a20;
  float b12 = a02 * a10 - a00 * a12;
  float b20 = a10 * a21 - a11 * a20;
  float b21 = a01 * a20 - a00 * a21;
  float b22 = a00 * a11 - a01 * a10;

  float det = a00 * b00 + a01 * b10 + a02 * b20;
  float rdet = 1.0f / det;

  b00 *= rdet; b01 *= rdet; b02 *= rdet;
  b10 *= rdet; b11 *= rdet; b12 *= rdet;
  b20 *= rdet; b21 *= rdet; b22 *= rdet;

  float4 o0, o1, o2;
  o0.x = b00 - 1.0f; o0.y = b01;        o0.z = b02;
  o0.w = -(b00 * t0 + b01 * t1 + b02 * t2);
  o1.x = b10;        o1.y = b11 - 1.0f; o1.z = b12;
  o1.w = -(b10 * t0 + b11 * t1 + b12 * t2);
  o2.x = b20;        o2.y = b21;        o2.z = b22 - 1.0f;
  o2.w = -(b20 * t0 + b21 * t1 + b22 * t2);

  out[3 * i + 0] = o0;
  out[3 * i + 1] = o1;
  out[3 * i + 2] = o2;
}

extern "C" void kernel_launch(void* const* d_in, const int* in_sizes, int n_in,
                              void* d_out, int out_size, void* d_ws, size_t ws_size,
                              hipStream_t stream) {
  const float4* trf = (const float4*)d_in[0];
  float4* out = (float4*)d_out;
  int b = in_sizes[0] / 12;  // 2,000,000 samples
  const int threads = 256;
  int blocks = (b + threads - 1) / threads;
  invert_affine_kernel<<<blocks, threads, 0, stream>>>(trf, out, b);
}

// Round 2
// 168.248 us; speedup vs baseline: 1.0181x; 1.0181x over previous
//
#include <hip/hip_runtime.h>

// InvertAffine: per sample, full = [[I+M, t],[0,1]] (4x4). Inverse is
// [[B, -B t],[0,1]] with B = (I+M)^{-1} via 3x3 cofactors.
// Memory-bound: 2M * 96 B = 192 MB total HBM traffic, floor ~30 us.
//
// R1: stage via LDS so global loads/stores are fully coalesced (16B/lane,
// consecutive lanes -> consecutive addresses). The R0 direct version's
// 48B-strided float4 accesses caused ~3x L1 line-transaction amplification
// (each vmem instr touched ~48 lines vs 16) -> 2.4 TB/s plateau.
// LDS layout: 768 float4 per block (12 KB). Compute-phase ds_read_b128 at
// 48B/lane stride is conflict-free (lane groups of 8 tile all 32 banks).

__global__ __launch_bounds__(256, 8) void invert_affine_kernel(
    const float4* __restrict__ in, float4* __restrict__ out, int b) {
  __shared__ float4 buf[768];  // 256 samples * 3 float4 = 12 KB

  const int tid = threadIdx.x;
  const int base_s = blockIdx.x * 256;      // first sample of this block
  const int base_f4 = base_s * 3;           // first float4 of this block
  const int n_f4 = b * 3;

  // coalesced global -> LDS
#pragma unroll
  for (int k = 0; k < 3; ++k) {
    int idx = base_f4 + k * 256 + tid;
    if (idx < n_f4) buf[k * 256 + tid] = in[idx];
  }
  __syncthreads();

  const int s = base_s + tid;
  if (s < b) {
    float4 r0 = buf[tid * 3 + 0];
    float4 r1 = buf[tid * 3 + 1];
    float4 r2 = buf[tid * 3 + 2];

    float a00 = r0.x + 1.0f, a01 = r0.y,        a02 = r0.z,        t0 = r0.w;
    float a10 = r1.x,        a11 = r1.y + 1.0f, a12 = r1.z,        t1 = r1.w;
    float a20 = r2.x,        a21 = r2.y,        a22 = r2.z + 1.0f, t2 = r2.w;

    float b00 = a11 * a22 - a12 * a21;
    float b01 = a02 * a21 - a01 * a22;
    float b02 = a01 * a12 - a02 * a11;
    float b10 = a12 * a20 - a10 * a22;
    float b11 = a00 * a22 - a02 * a20;
    float b12 = a02 * a10 - a00 * a12;
    float b20 = a10 * a21 - a11 * a20;
    float b21 = a01 * a20 - a00 * a21;
    float b22 = a00 * a11 - a01 * a10;

    float det = a00 * b00 + a01 * b10 + a02 * b20;
    float rdet = 1.0f / det;

    b00 *= rdet; b01 *= rdet; b02 *= rdet;
    b10 *= rdet; b11 *= rdet; b12 *= rdet;
    b20 *= rdet; b21 *= rdet; b22 *= rdet;

    float4 o0, o1, o2;
    o0.x = b00 - 1.0f; o0.y = b01;        o0.z = b02;
    o0.w = -(b00 * t0 + b01 * t1 + b02 * t2);
    o1.x = b10;        o1.y = b11 - 1.0f; o1.z = b12;
    o1.w = -(b10 * t0 + b11 * t1 + b12 * t2);
    o2.x = b20;        o2.y = b21;        o2.z = b22 - 1.0f;
    o2.w = -(b20 * t0 + b21 * t1 + b22 * t2);

    buf[tid * 3 + 0] = o0;
    buf[tid * 3 + 1] = o1;
    buf[tid * 3 + 2] = o2;
  }
  __syncthreads();

  // coalesced LDS -> global
#pragma unroll
  for (int k = 0; k < 3; ++k) {
    int idx = base_f4 + k * 256 + tid;
    if (idx < n_f4) out[idx] = buf[k * 256 + tid];
  }
}

extern "C" void kernel_launch(void* const* d_in, const int* in_sizes, int n_in,
                              void* d_out, int out_size, void* d_ws, size_t ws_size,
                              hipStream_t stream) {
  const float4* trf = (const float4*)d_in[0];
  float4* out = (float4*)d_out;
  int b = in_sizes[0] / 12;  // 2,000,000 samples
  const int threads = 256;
  int blocks = (b + threads - 1) / threads;  // 7813
  invert_affine_kernel<<<blocks, threads, 0, stream>>>(trf, out, b);
}